// Round 12
// baseline (71.950 us; speedup 1.0000x reference)
//
#include <hip/hip_runtime.h>

typedef _Float16 f16x8 __attribute__((ext_vector_type(8)));
typedef __attribute__((ext_vector_type(4))) float f32x4;
typedef unsigned short u16;

__device__ __forceinline__ u16 f2h(float f) {
    _Float16 h = (_Float16)f;
    return __builtin_bit_cast(u16, h);
}

// async global->LDS, 16B per lane; LDS dest = wave-uniform base + lane*16
#define GLDS(G, LBYTE)                                                         \
    __builtin_amdgcn_global_load_lds(                                          \
        (const __attribute__((address_space(1))) void*)(G),                    \
        (__attribute__((address_space(3))) void*)((char*)lds + (LBYTE)),       \
        16, 0, 0)

// NT GEMM, fp16 inputs: C[m,n] = sum_k A[m,k]*B[n,k]   (A:[M,K], B:[N,K] fp16)
// Tile 128 x (32*JW), BK=64, 256 threads = 4 waves (2x2), wave = 64 x (16*JW).
//   JW=2: wave 64x32, acc 4x2, LDS buf 24KB, 3 blocks/CU  (latency-friendly)
//   JW=4: wave 64x64, acc 4x4, LDS buf 32KB, 2 blocks/CU  (LDS-BW-friendly:
//         0.5 frag-reads/MFMA vs 0.75 — LDS bandwidth is the measured
//         bottleneck, r11 model: util ceiling 27% -> ~40%)
// fp32 accumulate via v_mfma_f32_16x16x32_f16.
// Double-buffered LDS, 2-phase pipeline: STAGE(next) BEFORE compute(cur).
// LDS rows 128B (8 x 16B slots), XOR-swizzled slot ^= row&7 (0-conflict,
// r4/r7 measured). Pre-swizzled GLOBAL source + same XOR on read; LDS dest
// of global_load_lds stays linear. XCD-aware bijective block swizzle.
// OUT: 0 = fp32, 1 = fp16.
// TW (OUT==1, M batched by 512): also write C transposed per batch CT[b][n][q].
// RS: epilogue v = acc + bias[n]*(1 - rs[row])  (fused trans-linear identity).
template<int JW, int OUT, bool BIAS, bool RELU, bool RS, bool TW, int GX, int GY>
__global__ __launch_bounds__(256, JW == 4 ? 2 : 3)
void gemm_nt(const u16* __restrict__ A, const u16* __restrict__ B,
             const float* __restrict__ bias, const float* __restrict__ rs,
             void* __restrict__ Cv, u16* __restrict__ CT,
             int K, int lda, int ldb, int ldc,
             long sA, long sB, long sC)
{
    __shared__ u16 lds[JW == 4 ? 32768 : 24576];
    constexpr int TN   = 32 * JW;               // tile N
    constexpr int BOF  = 8192;                  // B section offset (u16): A=16KB
    constexpr int BUFB = JW == 4 ? 32768 : 24576;  // buffer stride (bytes)
    constexpr int BUFE = BUFB / 2;              // buffer stride (u16)

    // ---- XCD-aware bijective block swizzle (nwg % 8 == 0 for all our grids)
    const unsigned flat = blockIdx.x;
    const unsigned cpx  = gridDim.x >> 3;
    const unsigned id   = (flat & 7u) * cpx + (flat >> 3);
    const int bz  = (int)(id / (unsigned)(GX * GY));
    const int rem = (int)(id - (unsigned)bz * (GX * GY));
    const int by  = rem / GX;
    const int bx  = rem - by * GX;

    const int tid  = threadIdx.x;
    const int lane = tid & 63;
    const int wid  = tid >> 6;
    const int m0 = by * 128;
    const int n0 = bx * TN;

    // staging map: thread t -> chunk row t>>3 (32 rows of 128B per 4KB chunk),
    // logical slot sl = (t&7) ^ (row&7); linear LDS dest, swizzled global src.
    const int rowS = tid >> 3;                    // 0..31
    const int sl   = (tid & 7) ^ (rowS & 7);      // logical 16B slot
    const unsigned ldsW = (unsigned)wid * 1024u;  // wave base within 4KB chunk

    const u16* aS = A + (size_t)bz * sA + ((size_t)m0 + rowS) * lda + sl * 8;
    const u16* bS = B + (size_t)bz * sB + ((size_t)n0 + rowS) * ldb + sl * 8;

    const int wm = (wid & 1) * 64;        // wave row in tile
    const int wn = (wid >> 1) * (16 * JW);// wave col in tile
    const int fr = lane & 15;             // fragment row within 16
    const int fq = lane >> 4;             // fragment k-quad (0..3)

    f32x4 acc[4][JW] = {};

    auto stage = [&](int bb, int k0) {
        // A: 128 rows x 128B = 4 chunks; B: TN rows x 128B = JW chunks
        GLDS(aS + k0,            bb +     0 + ldsW);
        GLDS(aS + k0 + 32 * lda, bb +  4096 + ldsW);
        GLDS(aS + k0 + 64 * lda, bb +  8192 + ldsW);
        GLDS(aS + k0 + 96 * lda, bb + 12288 + ldsW);
#pragma unroll
        for (int c = 0; c < JW; ++c)
            GLDS(bS + k0 + 32 * c * ldb, bb + 16384 + 4096 * c + ldsW);
    };

    auto compute = [&](int be) {  // be = u16 element offset of buffer
#pragma unroll
        for (int w = 0; w < 2; ++w) {
            const int sw = (((w << 2) | fq) ^ (fr & 7)) << 3;
            f16x8 vah[4], vbh[JW];
#pragma unroll
            for (int i = 0; i < 4; ++i)
                vah[i] = *(const f16x8*)(lds + be + (wm + i * 16 + fr) * 64 + sw);
#pragma unroll
            for (int j = 0; j < JW; ++j)
                vbh[j] = *(const f16x8*)(lds + be + BOF + (wn + j * 16 + fr) * 64 + sw);
#pragma unroll
            for (int i = 0; i < 4; ++i)
#pragma unroll
                for (int j = 0; j < JW; ++j)
                    acc[i][j] = __builtin_amdgcn_mfma_f32_16x16x32_f16(vah[i], vbh[j], acc[i][j], 0, 0, 0);
        }
    };

    // ---- 2-phase pipelined K-loop (K is a multiple of 128 for all calls)
    stage(0, 0);
    __syncthreads();                       // vmcnt(0) drain: buf0 ready
    for (int k0 = 0; k0 < K; k0 += 128) {
        if (k0 + 64 < K) stage(BUFB, k0 + 64);   // prefetch into buf1
        compute(0);                               // compute buf0
        __syncthreads();                          // buf1 ready; buf0 free
        if (k0 + 128 < K) stage(0, k0 + 128);
        compute(BUFE);                            // compute buf1
        __syncthreads();
    }

    float bj[JW];
    if (BIAS) {
#pragma unroll
        for (int j = 0; j < JW; ++j) bj[j] = bias[n0 + wn + j * 16 + fr];
    }
    const long crow0 = m0 + wm + fq * 4;
    const long ccol0 = n0 + wn + fr;
    float* Cf = (float*)Cv + (size_t)bz * sC;
    u16*   Ch = (u16*)Cv   + (size_t)bz * sC;
    const float* rsb = RS ? (rs + (size_t)bz * 512) : nullptr;
    // TW: batch of this tile (M batched by 512; 128-tiles never straddle)
    const int  bzT = (int)(crow0 >> 9);
    const long qb  = crow0 & 511;
#pragma unroll
    for (int i = 0; i < 4; ++i) {
        float rsv[4];
        if (RS) {
#pragma unroll
            for (int r = 0; r < 4; ++r) rsv[r] = 1.0f - rsb[crow0 + i * 16 + r];
        }
#pragma unroll
        for (int j = 0; j < JW; ++j) {
            ushort4 tw;
#pragma unroll
            for (int r = 0; r < 4; ++r) {
                float v = acc[i][j][r];
                if (BIAS) v += RS ? bj[j] * rsv[r] : bj[j];
                if (RELU) v = fmaxf(v, 0.0f);
                const size_t idx = (size_t)(crow0 + i * 16 + r) * ldc + ccol0 + j * 16;
                if (OUT == 0) Cf[idx] = v;
                else {
                    const u16 h = f2h(v);
                    Ch[idx] = h;
                    if (TW) (&tw.x)[r] = h;
                }
            }
            if (OUT == 1 && TW) {
                // CT[bzT][ccol0 + j*16][qb + i*16 .. +3]
                *(ushort4*)(CT + (size_t)bzT * 768 * 512
                               + (size_t)(ccol0 + j * 16) * 512 + qb + i * 16) = tw;
            }
        }
    }
}

// fused fp32 -> fp16 conversions: pq, pp (n4 float4s each) and W (nW4 float4s)
__global__ __launch_bounds__(256)
void cvt_all(const float* __restrict__ x0, u16* __restrict__ y0,
             const float* __restrict__ x1, u16* __restrict__ y1, int n4,
             const float* __restrict__ xw, u16* __restrict__ yw, int nW4)
{
    int i = blockIdx.x * 256 + threadIdx.x;
    const int stride = gridDim.x * 256;
    for (; i < n4; i += stride) {
        float4 v0 = ((const float4*)x0)[i];
        float4 v1 = ((const float4*)x1)[i];
        ushort4 h0, h1;
        h0.x = f2h(v0.x); h0.y = f2h(v0.y); h0.z = f2h(v0.z); h0.w = f2h(v0.w);
        h1.x = f2h(v1.x); h1.y = f2h(v1.y); h1.z = f2h(v1.z); h1.w = f2h(v1.w);
        ((ushort4*)y0)[i] = h0;
        ((ushort4*)y1)[i] = h1;
        if (i < nW4) {
            float4 vw = ((const float4*)xw)[i];
            ushort4 hw;
            hw.x = f2h(vw.x); hw.y = f2h(vw.y); hw.z = f2h(vw.z); hw.w = f2h(vw.w);
            ((ushort4*)yw)[i] = hw;
        }
    }
}

// MedLane masked softmax over 512 (fp32 in), writes fp16 probs in place
// (row stride stays 512 floats = 1024 u16 elements) + rs[row] = S/(S+1e-13).
// 2 reductions: masked entries contribute exactly exp(-M) each to Z, so
//   Z = sve + (512-L)*exp(-M),  S = sve/Z   (analytic; no third reduction).
__global__ __launch_bounds__(256)
void softmax_kernel(float* __restrict__ att, const int* __restrict__ seq_len,
                    float* __restrict__ rsout)
{
    const int row = blockIdx.x;
    const int b   = row >> 9;
    float* s = att + (size_t)row * 512;
    const int L = seq_len[b];
    const int tid = threadIdx.x;

    __shared__ float red[4];

    const float v0 = s[tid];
    const float v1 = s[tid + 256];
    const bool  k0 = (tid < L);
    const bool  k1 = (tid + 256 < L);
    const float s0 = k0 ? v0 : 0.0f;
    const float s1 = k1 ? v1 : 0.0f;

    float m = fmaxf(s0, s1);
#pragma unroll
    for (int o = 32; o > 0; o >>= 1) m = fmaxf(m, __shfl_down(m, o));
    if ((tid & 63) == 0) red[tid >> 6] = m;
    __syncthreads();
    const float M = fmaxf(fmaxf(red[0], red[1]), fmaxf(red[2], red[3]));
    __syncthreads();

    const float e0 = k0 ? expf(s0 - M) : 0.0f;
    const float e1 = k1 ? expf(s1 - M) : 0.0f;

    float zs = e0 + e1;
#pragma unroll
    for (int o = 32; o > 0; o >>= 1) zs += __shfl_down(zs, o);
    if ((tid & 63) == 0) red[tid >> 6] = zs;
    __syncthreads();
    const float sve = red[0] + red[1] + red[2] + red[3];

    const float Z   = sve + (float)(512 - L) * expf(-M);
    const float S   = sve / Z;
    const float inv = 1.0f / (S + 1e-13f);
    const float sc  = inv / Z;

    u16* o16 = (u16*)s;
    o16[tid]       = f2h(k0 ? e0 * sc : 0.0f);
    o16[tid + 256] = f2h(k1 ? e1 * sc : 0.0f);
    if (tid == 0) rsout[row] = S * inv;
}

extern "C" void kernel_launch(void* const* d_in, const int* in_sizes, int n_in,
                              void* d_out, int out_size, void* d_ws, size_t ws_size,
                              hipStream_t stream)
{
    (void)in_sizes; (void)n_in; (void)out_size; (void)ws_size;
    constexpr int B = 16, L = 512, H = 768;
    constexpr size_t NPQ = (size_t)B * L * H;   // 6291456
    constexpr size_t NW  = (size_t)H * H;       // 589824

    const float* proj_p  = (const float*)d_in[0];
    const float* proj_q  = (const float*)d_in[1];
    const int*   seq_len = (const int*)d_in[2];
    const float* W       = (const float*)d_in[3];
    const float* bias    = (const float*)d_in[4];
    float* out = (float*)d_out;

    // workspace (u16 elements): pq16 | pp16 | W16 | tqT | att | rs
    u16* ws   = (u16*)d_ws;
    u16* pq16 = ws;                    // [B,512,768] fp16
    u16* pp16 = pq16 + NPQ;            // [B,512,768] fp16
    u16* W16  = pp16 + NPQ;            // [768,768] fp16
    u16* tqT  = W16 + NW;              // [B,768,512] fp16 (trans_q transposed)
    float* att = (float*)(tqT + NPQ);  // [B,512,512] fp32 -> probs fp16 in place
    float* rs  = att + (size_t)B * L * L;  // [B,512] fp32 row sums

    // trans_q fp16 lives in d_out's first half (dead before final GEMM writes)
    u16* tq16 = (u16*)d_out;

    // 1) all fp16 conversions in one dispatch
    cvt_all<<<2048, 256, 0, stream>>>(proj_q, pq16, proj_p, pp16, (int)(NPQ / 4),
                                      W, W16, (int)(NW / 4));

    // 2) tq16 = pq @ W^T + bias  (fp16 out, dual row-major + transposed write)
    //    128x128 tile (JW=4): grid 6x64 = 384
    gemm_nt<4, 1, true, false, false, true, 6, 64><<<384, 256, 0, stream>>>(
        pq16, W16, bias, nullptr, tq16, tqT, H, H, H, H, 0, 0, 0);

    // 3) att[b] = pp[b] @ tq[b]^T  (fp32 out)  128x64 tile: grid 8x4x16 = 512
    //    (N=512 -> 128x128 would drop grid to 256 = 1/CU: starvation. Keep JW=2.)
    gemm_nt<2, 0, false, false, false, false, 8, 4><<<512, 256, 0, stream>>>(
        pp16, tq16, nullptr, nullptr, att, nullptr, H, H, H, L,
        (long)L * H, (long)L * H, (long)L * L);

    // 4) masked softmax (2-reduction), fp16 probs in place + rs
    softmax_kernel<<<B * L, 256, 0, stream>>>(att, seq_len, rs);

    // 5) out = relu(probs @ tqT^T + bias*(1-rs))  128x128 tile: grid 6x4x16 = 384
    //    (algebraic fusion: (probs@pq)@W^T + b == probs@tq + b*(1-sum(probs)))
    gemm_nt<4, 0, true, true, true, false, 6, 4><<<384, 256, 0, stream>>>(
        (const u16*)att, tqT, bias, rs, out, nullptr,
        L, 1024, L, H, (long)L * 1024, (long)H * L, (long)L * H);
}

// Round 13
// 68.337 us; speedup vs baseline: 1.0529x; 1.0529x over previous
//
#include <hip/hip_runtime.h>

typedef _Float16 f16x8 __attribute__((ext_vector_type(8)));
typedef __attribute__((ext_vector_type(4))) float f32x4;
typedef unsigned short u16;

__device__ __forceinline__ u16 f2h(float f) {
    _Float16 h = (_Float16)f;
    return __builtin_bit_cast(u16, h);
}

__device__ __forceinline__ f16x8 cvt8(float4 a, float4 b) {
    f16x8 r;
    r[0] = (_Float16)a.x; r[1] = (_Float16)a.y; r[2] = (_Float16)a.z; r[3] = (_Float16)a.w;
    r[4] = (_Float16)b.x; r[5] = (_Float16)b.y; r[6] = (_Float16)b.z; r[7] = (_Float16)b.w;
    return r;
}

// raw barrier: ds_writes must be visible (lgkmcnt), but register global-loads
// may stay in flight (NO vmcnt drain — that's the whole point vs __syncthreads)
#define LGKM0_BAR()                                                            \
    do {                                                                       \
        asm volatile("s_waitcnt lgkmcnt(0)" ::: "memory");                     \
        __builtin_amdgcn_s_barrier();                                          \
    } while (0)

// NT GEMM with FUSED fp32->fp16 staging: C[m,n] = sum_k A[m,k]*B[n,k]
// A:[M,K], B:[N,K]; AF32/BF32 select fp32 (convert-on-stage) vs fp16 source.
// 128x64 tile, BK=64, 256 threads = 4 waves (2x2 of 64x32, acc 4x2),
// v_mfma_f32_16x16x32_f16, fp32 accumulate.
// REG-STAGED double-buffered pipeline (T14 split):
//   loads for tile t+1 are issued one full compute-phase before their
//   cvt+ds_write consumes them; raw s_barrier + lgkmcnt(0) between steps so
//   in-flight register loads cross the barrier (no vmcnt(0) drain).
// LDS rows 128B (8 x 16B slots), XOR swizzle slot = colgrp ^ (row&7) applied
// on the WRITE side (we own the ds_write addr now); read side unchanged —
// same physical layout as r4/r7/r11 (measured 0-conflict).
// XCD-aware bijective block swizzle. OUT: 0=fp32, 1=fp16.
// TW (OUT==1, M batched by 512): also write C transposed per batch CT[b][n][q].
// RS: epilogue v = acc + bias[n]*(1 - rs[row]) (fused trans-linear identity).
template<bool AF32, bool BF32, int OUT, bool BIAS, bool RELU, bool RS, bool TW,
         int GX, int GY>
__global__ __launch_bounds__(256, 3)
void gemm_nt(const void* __restrict__ Av, const void* __restrict__ Bv,
             const float* __restrict__ bias, const float* __restrict__ rs,
             void* __restrict__ Cv, u16* __restrict__ CT,
             int K, int lda, int ldb, int ldc,
             long sA, long sB, long sC)
{
    __shared__ u16 lds[24576];   // 48KB = 2 buffers x 24KB
    constexpr int BOF  = 8192;   // B section offset (u16): A = 16KB
    constexpr int BUFE = 12288;  // buffer stride (u16 elems)

    // ---- XCD-aware bijective block swizzle (nwg % 8 == 0 for all our grids)
    const unsigned flat = blockIdx.x;
    const unsigned cpx  = gridDim.x >> 3;
    const unsigned id   = (flat & 7u) * cpx + (flat >> 3);
    const int bz  = (int)(id / (unsigned)(GX * GY));
    const int rem = (int)(id - (unsigned)bz * (GX * GY));
    const int by  = rem / GX;
    const int bx  = rem - by * GX;

    const int tid  = threadIdx.x;
    const int lane = tid & 63;
    const int wid  = tid >> 6;
    const int m0 = by * 128;
    const int n0 = bx * 64;

    // staging map: thread t -> row rowS (0..31 per 32-row chunk),
    // LINEAR global col group cg, ds_write slot slw = cg ^ (rowS&7).
    const int rowS = tid >> 3;
    const int cg   = tid & 7;
    const int slw  = cg ^ (rowS & 7);

    const float* aF = nullptr; const u16* aH = nullptr;
    const float* bF = nullptr; const u16* bH = nullptr;
    if constexpr (AF32)
        aF = (const float*)Av + (size_t)bz * sA + ((size_t)(m0 + rowS)) * lda + cg * 8;
    else
        aH = (const u16*)Av + (size_t)bz * sA + ((size_t)(m0 + rowS)) * lda + cg * 8;
    if constexpr (BF32)
        bF = (const float*)Bv + (size_t)bz * sB + ((size_t)(n0 + rowS)) * ldb + cg * 8;
    else
        bH = (const u16*)Bv + (size_t)bz * sB + ((size_t)(n0 + rowS)) * ldb + cg * 8;

    const int wm = (wid & 1) * 64;        // wave row in tile
    const int wn = (wid >> 1) * 32;       // wave col in tile
    const int fr = lane & 15;             // fragment row within 16
    const int fq = lane >> 4;             // fragment k-quad (0..3)

    f32x4 acc[4][2] = {};

    // staged-tile registers (held across one compute phase)
    float4 rA[8]; f16x8 hA[4];
    float4 rB[4]; f16x8 hB[2];

    auto loadT = [&](int k0) {   // issue global loads, no wait
        if constexpr (AF32) {
#pragma unroll
            for (int c = 0; c < 4; ++c) {
                const float* p = aF + (size_t)(c * 32) * lda + k0;
                rA[2 * c]     = *(const float4*)p;
                rA[2 * c + 1] = *(const float4*)(p + 4);
            }
        } else {
#pragma unroll
            for (int c = 0; c < 4; ++c)
                hA[c] = *(const f16x8*)(aH + (size_t)(c * 32) * lda + k0);
        }
        if constexpr (BF32) {
#pragma unroll
            for (int c = 0; c < 2; ++c) {
                const float* p = bF + (size_t)(c * 32) * ldb + k0;
                rB[2 * c]     = *(const float4*)p;
                rB[2 * c + 1] = *(const float4*)(p + 4);
            }
        } else {
#pragma unroll
            for (int c = 0; c < 2; ++c)
                hB[c] = *(const f16x8*)(bH + (size_t)(c * 32) * ldb + k0);
        }
    };

    auto writeT = [&](int be) {  // cvt + swizzled ds_write (waits own loads)
#pragma unroll
        for (int c = 0; c < 4; ++c) {
            f16x8 v;
            if constexpr (AF32) v = cvt8(rA[2 * c], rA[2 * c + 1]);
            else                v = hA[c];
            *(f16x8*)(lds + be + (c * 32 + rowS) * 64 + slw * 8) = v;
        }
#pragma unroll
        for (int c = 0; c < 2; ++c) {
            f16x8 v;
            if constexpr (BF32) v = cvt8(rB[2 * c], rB[2 * c + 1]);
            else                v = hB[c];
            *(f16x8*)(lds + be + BOF + (c * 32 + rowS) * 64 + slw * 8) = v;
        }
    };

    auto compute = [&](int be) {
#pragma unroll
        for (int w = 0; w < 2; ++w) {
            const int sw = (((w << 2) | fq) ^ (fr & 7)) << 3;
            f16x8 vah[4], vbh[2];
#pragma unroll
            for (int i = 0; i < 4; ++i)
                vah[i] = *(const f16x8*)(lds + be + (wm + i * 16 + fr) * 64 + sw);
#pragma unroll
            for (int j = 0; j < 2; ++j)
                vbh[j] = *(const f16x8*)(lds + be + BOF + (wn + j * 16 + fr) * 64 + sw);
#pragma unroll
            for (int i = 0; i < 4; ++i)
#pragma unroll
                for (int j = 0; j < 2; ++j)
                    acc[i][j] = __builtin_amdgcn_mfma_f32_16x16x32_f16(vah[i], vbh[j], acc[i][j], 0, 0, 0);
        }
    };

    // ---- reg-staged 2-buffer pipeline (K multiple of 128 for all calls)
    loadT(0);
    writeT(0);          // waits tile0 loads
    loadT(64);          // tile1 in flight
    LGKM0_BAR();
    for (int k0 = 0; k0 < K; k0 += 128) {
        compute(0);
        writeT(BUFE);                       // tile k0+64 (loads landed under compute)
        if (k0 + 128 < K) loadT(k0 + 128);  // issue next, crosses barrier
        LGKM0_BAR();
        compute(BUFE);
        if (k0 + 128 < K) {
            writeT(0);                      // tile k0+128
            if (k0 + 192 < K) loadT(k0 + 192);
        }
        LGKM0_BAR();
    }

    float bj[2];
    if (BIAS) {
#pragma unroll
        for (int j = 0; j < 2; ++j) bj[j] = bias[n0 + wn + j * 16 + fr];
    }
    const long crow0 = m0 + wm + fq * 4;
    const long ccol0 = n0 + wn + fr;
    float* Cf = (float*)Cv + (size_t)bz * sC;
    u16*   Ch = (u16*)Cv   + (size_t)bz * sC;
    const float* rsb = RS ? (rs + (size_t)bz * 512) : nullptr;
    const int  bzT = (int)(crow0 >> 9);   // TW: batch (M batched by 512)
    const long qb  = crow0 & 511;
#pragma unroll
    for (int i = 0; i < 4; ++i) {
        float rsv[4];
        if (RS) {
#pragma unroll
            for (int r = 0; r < 4; ++r) rsv[r] = 1.0f - rsb[crow0 + i * 16 + r];
        }
#pragma unroll
        for (int j = 0; j < 2; ++j) {
            ushort4 tw;
#pragma unroll
            for (int r = 0; r < 4; ++r) {
                float v = acc[i][j][r];
                if (BIAS) v += RS ? bj[j] * rsv[r] : bj[j];
                if (RELU) v = fmaxf(v, 0.0f);
                const size_t idx = (size_t)(crow0 + i * 16 + r) * ldc + ccol0 + j * 16;
                if (OUT == 0) Cf[idx] = v;
                else {
                    const u16 h = f2h(v);
                    Ch[idx] = h;
                    if (TW) (&tw.x)[r] = h;
                }
            }
            if (OUT == 1 && TW) {
                *(ushort4*)(CT + (size_t)bzT * 768 * 512
                               + (size_t)(ccol0 + j * 16) * 512 + qb + i * 16) = tw;
            }
        }
    }
}

// MedLane masked softmax over 512 (fp32 in), writes fp16 probs in place
// (row stride stays 512 floats = 1024 u16 elements) + rs[row] = S/(S+1e-13).
// 2 reductions: masked entries contribute exactly exp(-M) each to Z, so
//   Z = sve + (512-L)*exp(-M),  S = sve/Z   (analytic; no third reduction).
__global__ __launch_bounds__(256)
void softmax_kernel(float* __restrict__ att, const int* __restrict__ seq_len,
                    float* __restrict__ rsout)
{
    const int row = blockIdx.x;
    const int b   = row >> 9;
    float* s = att + (size_t)row * 512;
    const int L = seq_len[b];
    const int tid = threadIdx.x;

    __shared__ float red[4];

    const float v0 = s[tid];
    const float v1 = s[tid + 256];
    const bool  k0 = (tid < L);
    const bool  k1 = (tid + 256 < L);
    const float s0 = k0 ? v0 : 0.0f;
    const float s1 = k1 ? v1 : 0.0f;

    float m = fmaxf(s0, s1);
#pragma unroll
    for (int o = 32; o > 0; o >>= 1) m = fmaxf(m, __shfl_down(m, o));
    if ((tid & 63) == 0) red[tid >> 6] = m;
    __syncthreads();
    const float M = fmaxf(fmaxf(red[0], red[1]), fmaxf(red[2], red[3]));
    __syncthreads();

    const float e0 = k0 ? expf(s0 - M) : 0.0f;
    const float e1 = k1 ? expf(s1 - M) : 0.0f;

    float zs = e0 + e1;
#pragma unroll
    for (int o = 32; o > 0; o >>= 1) zs += __shfl_down(zs, o);
    if ((tid & 63) == 0) red[tid >> 6] = zs;
    __syncthreads();
    const float sve = red[0] + red[1] + red[2] + red[3];

    const float Z   = sve + (float)(512 - L) * expf(-M);
    const float S   = sve / Z;
    const float inv = 1.0f / (S + 1e-13f);
    const float sc  = inv / Z;

    u16* o16 = (u16*)s;
    o16[tid]       = f2h(k0 ? e0 * sc : 0.0f);
    o16[tid + 256] = f2h(k1 ? e1 * sc : 0.0f);
    if (tid == 0) rsout[row] = S * inv;
}

extern "C" void kernel_launch(void* const* d_in, const int* in_sizes, int n_in,
                              void* d_out, int out_size, void* d_ws, size_t ws_size,
                              hipStream_t stream)
{
    (void)in_sizes; (void)n_in; (void)out_size; (void)ws_size;
    constexpr int B = 16, L = 512, H = 768;
    constexpr size_t NPQ = (size_t)B * L * H;   // 6291456

    const float* proj_p  = (const float*)d_in[0];
    const float* proj_q  = (const float*)d_in[1];
    const int*   seq_len = (const int*)d_in[2];
    const float* W       = (const float*)d_in[3];
    const float* bias    = (const float*)d_in[4];
    float* out = (float*)d_out;

    // workspace (u16 elements): tqT | att | rs   (~29.4 MB of 64)
    u16* ws   = (u16*)d_ws;
    u16* tqT  = ws;                    // [B,768,512] fp16 (trans_q transposed)
    float* att = (float*)(tqT + NPQ);  // [B,512,512] fp32 -> probs fp16 in place
    float* rs  = att + (size_t)B * L * L;  // [B,512] fp32 row sums

    // trans_q fp16 lives in d_out's first half (dead before final GEMM writes)
    u16* tq16 = (u16*)d_out;

    // 1) tq16 = pq @ W^T + bias  (fp32 sources, cvt fused in staging;
    //    fp16 out, dual row-major + transposed write)  grid 12x64 = 768
    gemm_nt<true, true, 1, true, false, false, true, 12, 64><<<768, 256, 0, stream>>>(
        proj_q, W, bias, nullptr, tq16, tqT, H, H, H, H, 0, 0, 0);

    // 2) att[b] = pp[b] @ tq[b]^T  (pp fp32 cvt-fused, tq fp16; fp32 out)
    //    grid 8x4x16 = 512
    gemm_nt<true, false, 0, false, false, false, false, 8, 4><<<512, 256, 0, stream>>>(
        proj_p, tq16, nullptr, nullptr, att, nullptr, H, H, H, L,
        (long)L * H, (long)L * H, (long)L * L);

    // 3) masked softmax (2-reduction), fp16 probs in place + rs
    softmax_kernel<<<B * L, 256, 0, stream>>>(att, seq_len, rs);

    // 4) out = relu(probs @ tqT^T + bias*(1-rs))  grid 12x4x16 = 768
    //    (algebraic fusion: (probs@pq)@W^T + b == probs@tq + b*(1-sum(probs)))
    gemm_nt<false, false, 0, true, true, true, false, 12, 4><<<768, 256, 0, stream>>>(
        (const u16*)att, tqT, bias, rs, out, nullptr,
        L, 1024, L, H, (long)L * 1024, (long)H * L, (long)L * H);
}